// Round 16
// baseline (107.228 us; speedup 1.0000x reference)
//
#include <hip/hip_runtime.h>

#define S 24
#define PLANE 576
#define CISTRIDE 331776          // floats per (n,ci)
#define SLAB_B 21632             // full padded slab: 676 positions * 32 B
#define QSLAB_B 4992             // band window: 6 rows * 26 * 32 B
#define QOFF 3328                // 4 rows * 832 B
#define A_BYTES 46080            // 9 taps * 5 steps * 64 lanes * 16 B
#define WS_SLABS A_BYTES

typedef __attribute__((ext_vector_type(8))) short bf16x8;
typedef __attribute__((ext_vector_type(4))) float f32x4;

__device__ __forceinline__ ushort f2bf(float f) {   // round-to-nearest-even
    unsigned int u = __builtin_bit_cast(unsigned int, f);
    unsigned int r = u + 0x7fffu + ((u >> 16) & 1u);
    return (ushort)(r >> 16);
}

// ---------------- prepass: DMA-staged transpose to bf16 slabs (+ weights from block 0) ----
// slab layout: 16B chunk c for (row,col,half): byte = (c*16) ^ ((row&3)<<4), c=(row*26+col)*2+half
__global__ void __launch_bounds__(256)
pack_in(const float* __restrict__ in, const float* __restrict__ wgt, char* __restrict__ ws) {
    __shared__ __align__(16) float lds_f[16 * 576];   // 36864 B raw f32 planes

    const int b = blockIdx.x;             // 1152 slabs
    const int nb = b / PLANE, uv = b % PLANE;
    const float* src = in + (size_t)nb * 16 * CISTRIDE + (size_t)uv * PLANE;
    char* dst = ws + WS_SLABS + (size_t)b * SLAB_B;
    const int t = threadIdx.x;

    // phase 1: global->LDS DMA, 2304 16B chunks, no VGPR round-trip
    #pragma unroll
    for (int r = 0; r < 9; ++r) {
        int chunk = r * 256 + t;          // exact 9*256
        int ci = chunk / 144, q4 = chunk % 144;
        __builtin_amdgcn_global_load_lds(
            (const __attribute__((address_space(1))) unsigned int*)(src + (size_t)ci * CISTRIDE + 4 * q4),
            (__attribute__((address_space(3))) unsigned int*)(&lds_f[chunk * 4]),
            16, 0, 0);
    }
    __syncthreads();

    // phase 2: convert on read, pack 16 ci per position, swizzled coalesced stores
    #pragma unroll
    for (int i = 0; i < 6; ++i) {
        int c = i * 256 + t;              // chunk index 0..1351
        if (c < 1352) {
            int pos = c >> 1, h = c & 1;
            int row = pos / 26, col = pos % 26;
            uint4 o = make_uint4(0, 0, 0, 0);
            if (row >= 1 && row <= 24 && col >= 1 && col <= 24) {
                int q = (row - 1) * 24 + (col - 1);
                #pragma unroll
                for (int kk = 0; kk < 4; ++kk) {
                    float fa = lds_f[(8 * h + 2 * kk) * 576 + q];
                    float fb = lds_f[(8 * h + 2 * kk + 1) * 576 + q];
                    ((unsigned*)&o)[kk] = (unsigned)f2bf(fa) | ((unsigned)f2bf(fb) << 16);
                }
            }
            *(uint4*)(dst + (((size_t)c * 16) ^ (size_t)((row & 3) << 4))) = o;
        }
    }

    if (b == 0) {                        // weight A-fragments, 9 taps
        for (int i = t; i < 2880; i += 256) {
            int step = i >> 6;           // 0..44
            int tap = step / 5, s = step % 5;
            int lane = i & 63;
            int co = lane & 15, gA = lane >> 4;
            int o = 2 * s + (gA >> 1);
            int cib = (gA & 1) * 8;
            ushort vals[8];
            #pragma unroll
            for (int j = 0; j < 8; ++j)
                vals[j] = (o <= 8) ? f2bf(wgt[co * 1296 + (cib + j) * 81 + tap * 9 + o]) : (ushort)0;
            uint4 pk;
            pk.x = vals[0] | ((unsigned)vals[1] << 16);
            pk.y = vals[2] | ((unsigned)vals[3] << 16);
            pk.z = vals[4] | ((unsigned)vals[5] << 16);
            pk.w = vals[6] | ((unsigned)vals[7] << 16);
            *(uint4*)(ws + (size_t)i * 16) = pk;
        }
    }
}

// ---- main: G=4 v-adjacent outputs, 6 h-bands (4 rows), kv-sharing, 1728 blocks ----
__global__ void __launch_bounds__(192, 4)
conv4d_main(const char* __restrict__ ws, const float* __restrict__ bias,
            float* __restrict__ out) {
    __shared__ __align__(16) char lds[2 * QSLAB_B];   // 9984 B double buffer

    const int t = threadIdx.x, lane = t & 63, wvid = t >> 6;   // wave = 8-col band
    // XCD-chunked bijective swizzle: 1728 ids, 8 XCDs x 216 contiguous
    const int braw = blockIdx.x;
    const int b = (braw & 7) * 216 + (braw >> 3);
    const int nb = b / 864, rem = b % 864;
    const int u = rem / 36, rem2 = rem % 36;
    const int v0 = (rem2 / 6) * 4, qq = rem2 % 6;     // 4 v-slabs, 4-row band

    const int n16 = lane & 15, g = lane >> 4;
    const int dh = n16 >> 3, dw = n16 & 7;            // 2x8 position tile
    const int half = g & 1, osel = g >> 1;

    // per-(tr,s) B offsets; band base row = 4*qq ≡ 0 mod 4 -> phase = (2*tr + r_off)&3
    int loff[2][5];
    #pragma unroll
    for (int tr = 0; tr < 2; ++tr)
        #pragma unroll
        for (int s = 0; s < 5; ++s) {
            int o = 2 * s + osel; if (o > 8) o = 8;   // K-tail clamp (A is zero there)
            int kh = o / 3, kw = o % 3;
            int r_off = dh + kh, c_off = dw + kw;
            int lin = (r_off * 26 + c_off) * 32 + half * 16;
            loff[tr][s] = lin ^ (((tr * 2 + r_off) & 3) << 4);
        }

    f32x4 acc[4][2];
    #pragma unroll
    for (int a = 0; a < 4; ++a)
        #pragma unroll
        for (int tr = 0; tr < 2; ++tr) acc[a][tr] = (f32x4){0, 0, 0, 0};

    // window mask: i = ku*6 + vj ; uu = u+ku-1, vv = v0+vj-1
    unsigned mask = 0;
    #pragma unroll
    for (int i = 0; i < 18; ++i) {
        int uu = u + i / 6 - 1, vv = v0 + i % 6 - 1;
        if (uu >= 0 && uu < S && vv >= 0 && vv < S) mask |= 1u << i;
    }

    const char* slabs = ws + WS_SLABS;
    const size_t qoff = (size_t)qq * QOFF;
    #define SLAB_PTR(i_) (slabs + ((size_t)nb * PLANE + (u + (i_) / 6 - 1) * S + (v0 + (i_) % 6 - 1)) * SLAB_B + qoff)

    #define STAGE(bufsel_, src_) do {                                              \
        const char* _s = (src_);                                                   \
        _Pragma("unroll")                                                          \
        for (int r2 = 0; r2 < 2; ++r2) {                                           \
            int chunk = r2 * 192 + t;                                              \
            if (r2 < 1 || t < 120)                                                 \
                __builtin_amdgcn_global_load_lds(                                  \
                    (const __attribute__((address_space(1))) unsigned int*)(_s + (size_t)chunk * 16), \
                    (__attribute__((address_space(3))) unsigned int*)(lds + (bufsel_) * QSLAB_B + chunk * 16), \
                    16, 0, 0);                                                     \
        }                                                                          \
    } while (0)

    int first = __ffs(mask) - 1;
    STAGE(0, SLAB_PTR(first));
    __syncthreads();

    int cb = 0;
    bf16x8 afr[3][5];   // A-frags for current ku row (kv = 0..2), all indices static

    #pragma unroll
    for (int ku = 0; ku < 3; ++ku) {
        if (!((mask >> (ku * 6)) & 63u)) continue;    // block-uniform row skip
        #pragma unroll
        for (int kv = 0; kv < 3; ++kv) {
            const char* ap = ws + (size_t)(ku * 3 + kv) * 5120 + (size_t)lane * 16;
            #pragma unroll
            for (int s = 0; s < 5; ++s) afr[kv][s] = *(const bf16x8*)(ap + s * 1024);
        }
        #pragma unroll
        for (int vj = 0; vj < 6; ++vj) {
            const int i = ku * 6 + vj;
            if (!(mask & (1u << i))) continue;        // block-uniform
            unsigned rm = mask >> (i + 1);
            int nx = rm ? (i + 1 + __ffs(rm) - 1) : -1;
            if (nx >= 0) STAGE(cb ^ 1, SLAB_PTR(nx)); // overlaps compute below

            const char* bp = lds + cb * QSLAB_B + wvid * 256;
            #pragma unroll
            for (int tr = 0; tr < 2; ++tr) {
                #pragma unroll
                for (int s = 0; s < 5; ++s) {
                    bf16x8 bfr = *(const bf16x8*)(bp + tr * 1664 + loff[tr][s]);
                    #pragma unroll
                    for (int kv = 0; kv < 3; ++kv) {
                        const int a = vj - kv;        // output slab index
                        if (a >= 0 && a <= 3)
                            acc[a][tr] = __builtin_amdgcn_mfma_f32_16x16x32_bf16(afr[kv][s], bfr, acc[a][tr], 0, 0, 0);
                    }
                }
            }
            __syncthreads();
            cb ^= 1;
        }
    }

    // epilogue: C col = lane&15 -> (dh,dw); row = g*4+r -> c_out ; four v-slabs
    float bv[4];
    #pragma unroll
    for (int r = 0; r < 4; ++r) bv[r] = bias[g * 4 + r];
    #pragma unroll
    for (int a = 0; a < 4; ++a) {
        float* outp = out + (size_t)nb * 16 * CISTRIDE + (size_t)(u * S + v0 + a) * PLANE;
        #pragma unroll
        for (int tr = 0; tr < 2; ++tr) {
            int row = qq * 4 + tr * 2 + dh;
            int col = wvid * 8 + dw;
            int pos = row * S + col;
            #pragma unroll
            for (int r = 0; r < 4; ++r)
                outp[(size_t)(g * 4 + r) * CISTRIDE + pos] = acc[a][tr][r] + bv[r];
        }
    }
}

extern "C" void kernel_launch(void* const* d_in, const int* in_sizes, int n_in,
                              void* d_out, int out_size, void* d_ws, size_t ws_size,
                              hipStream_t stream) {
    const float* in   = (const float*)d_in[0];
    const float* wgt  = (const float*)d_in[1];
    const float* bias = (const float*)d_in[2];
    float* out        = (float*)d_out;
    char* ws          = (char*)d_ws;

    pack_in<<<dim3(1152), dim3(256), 0, stream>>>(in, wgt, ws);
    // MEASUREMENT ROUND: main launched twice (idempotent — same inputs, same output).
    // timed_total = pack + 2*main  =>  main = timed_total - R15_total (71.6 us).
    conv4d_main<<<dim3(1728), dim3(192), 0, stream>>>(ws, bias, out);
    conv4d_main<<<dim3(1728), dim3(192), 0, stream>>>(ws, bias, out);
}

// Round 17
// 104.982 us; speedup vs baseline: 1.0214x; 1.0214x over previous
//
#include <hip/hip_runtime.h>

#define S 24
#define PLANE 576
#define CISTRIDE 331776          // floats per (n,ci)
#define SLAB_B 21632             // full padded slab: 676 positions * 32 B
#define QSLAB_B 4992             // band window: 6 rows * 26 * 32 B
#define QOFF 3328                // 4 rows * 832 B
#define A_BYTES 46080            // 9 taps * 5 steps * 64 lanes * 16 B
#define WS_SLABS A_BYTES

typedef __attribute__((ext_vector_type(8))) short bf16x8;
typedef __attribute__((ext_vector_type(4))) float f32x4;

__device__ __forceinline__ ushort f2bf(float f) {   // round-to-nearest-even
    unsigned int u = __builtin_bit_cast(unsigned int, f);
    unsigned int r = u + 0x7fffu + ((u >> 16) & 1u);
    return (ushort)(r >> 16);
}

// ---------------- prepass: DMA-staged transpose to bf16 slabs (+ weights from block 0) ----
// slab layout: 16B chunk c for (row,col,half): byte = (c*16) ^ ((row&3)<<4), c=(row*26+col)*2+half
__global__ void __launch_bounds__(256)
pack_in(const float* __restrict__ in, const float* __restrict__ wgt, char* __restrict__ ws) {
    __shared__ __align__(16) float lds_f[16 * 576];   // 36864 B raw f32 planes

    const int b = blockIdx.x;             // 1152 slabs
    const int nb = b / PLANE, uv = b % PLANE;
    const float* src = in + (size_t)nb * 16 * CISTRIDE + (size_t)uv * PLANE;
    char* dst = ws + WS_SLABS + (size_t)b * SLAB_B;
    const int t = threadIdx.x;

    // phase 1: global->LDS DMA, 2304 16B chunks, no VGPR round-trip
    #pragma unroll
    for (int r = 0; r < 9; ++r) {
        int chunk = r * 256 + t;          // exact 9*256
        int ci = chunk / 144, q4 = chunk % 144;
        __builtin_amdgcn_global_load_lds(
            (const __attribute__((address_space(1))) unsigned int*)(src + (size_t)ci * CISTRIDE + 4 * q4),
            (__attribute__((address_space(3))) unsigned int*)(&lds_f[chunk * 4]),
            16, 0, 0);
    }
    __syncthreads();

    // phase 2: convert on read, pack 16 ci per position, swizzled coalesced stores
    #pragma unroll
    for (int i = 0; i < 6; ++i) {
        int c = i * 256 + t;              // chunk index 0..1351
        if (c < 1352) {
            int pos = c >> 1, h = c & 1;
            int row = pos / 26, col = pos % 26;
            uint4 o = make_uint4(0, 0, 0, 0);
            if (row >= 1 && row <= 24 && col >= 1 && col <= 24) {
                int q = (row - 1) * 24 + (col - 1);
                #pragma unroll
                for (int kk = 0; kk < 4; ++kk) {
                    float fa = lds_f[(8 * h + 2 * kk) * 576 + q];
                    float fb = lds_f[(8 * h + 2 * kk + 1) * 576 + q];
                    ((unsigned*)&o)[kk] = (unsigned)f2bf(fa) | ((unsigned)f2bf(fb) << 16);
                }
            }
            *(uint4*)(dst + (((size_t)c * 16) ^ (size_t)((row & 3) << 4))) = o;
        }
    }

    if (b == 0) {                        // weight A-fragments, 9 taps
        for (int i = t; i < 2880; i += 256) {
            int step = i >> 6;           // 0..44
            int tap = step / 5, s = step % 5;
            int lane = i & 63;
            int co = lane & 15, gA = lane >> 4;
            int o = 2 * s + (gA >> 1);
            int cib = (gA & 1) * 8;
            ushort vals[8];
            #pragma unroll
            for (int j = 0; j < 8; ++j)
                vals[j] = (o <= 8) ? f2bf(wgt[co * 1296 + (cib + j) * 81 + tap * 9 + o]) : (ushort)0;
            uint4 pk;
            pk.x = vals[0] | ((unsigned)vals[1] << 16);
            pk.y = vals[2] | ((unsigned)vals[3] << 16);
            pk.z = vals[4] | ((unsigned)vals[5] << 16);
            pk.w = vals[6] | ((unsigned)vals[7] << 16);
            *(uint4*)(ws + (size_t)i * 16) = pk;
        }
    }
}

// ---- main: G=4 v-adjacent outputs, 6 h-bands, T4 counted-vmcnt (stage 1 iter ahead) ----
__global__ void __launch_bounds__(192, 4)
conv4d_main(const char* __restrict__ ws, const float* __restrict__ bias,
            float* __restrict__ out) {
    __shared__ __align__(16) char lds[2 * QSLAB_B];   // 9984 B double buffer

    const int t = threadIdx.x, lane = t & 63, wvid = t >> 6;   // wave = 8-col band
    // XCD-chunked bijective swizzle: 1728 ids, 8 XCDs x 216 contiguous
    const int braw = blockIdx.x;
    const int b = (braw & 7) * 216 + (braw >> 3);
    const int nb = b / 864, rem = b % 864;
    const int u = rem / 36, rem2 = rem % 36;
    const int v0 = (rem2 / 6) * 4, qq = rem2 % 6;     // 4 v-slabs, 4-row band

    const int n16 = lane & 15, g = lane >> 4;
    const int dh = n16 >> 3, dw = n16 & 7;            // 2x8 position tile
    const int half = g & 1, osel = g >> 1;

    // per-(tr,s) B offsets; band base row = 4*qq ≡ 0 mod 4 -> phase = (2*tr + r_off)&3
    int loff[2][5];
    #pragma unroll
    for (int tr = 0; tr < 2; ++tr)
        #pragma unroll
        for (int s = 0; s < 5; ++s) {
            int o = 2 * s + osel; if (o > 8) o = 8;   // K-tail clamp (A is zero there)
            int kh = o / 3, kw = o % 3;
            int r_off = dh + kh, c_off = dw + kw;
            int lin = (r_off * 26 + c_off) * 32 + half * 16;
            loff[tr][s] = lin ^ (((tr * 2 + r_off) & 3) << 4);
        }

    f32x4 acc[4][2];
    #pragma unroll
    for (int a = 0; a < 4; ++a)
        #pragma unroll
        for (int tr = 0; tr < 2; ++tr) acc[a][tr] = (f32x4){0, 0, 0, 0};

    // window mask: i = ku*6 + vj ; uu = u+ku-1, vv = v0+vj-1
    unsigned mask = 0;
    #pragma unroll
    for (int i = 0; i < 18; ++i) {
        int uu = u + i / 6 - 1, vv = v0 + i % 6 - 1;
        if (uu >= 0 && uu < S && vv >= 0 && vv < S) mask |= 1u << i;
    }

    const char* slabs = ws + WS_SLABS;
    const size_t qoff = (size_t)qq * QOFF;
    #define SLAB_PTR(i_) (slabs + ((size_t)nb * PLANE + (u + (i_) / 6 - 1) * S + (v0 + (i_) % 6 - 1)) * SLAB_B + qoff)

    // STAGE = exactly 2 global_load_lds instructions per wave (vmcnt counting relies on this)
    #define STAGE(bufsel_, src_) do {                                              \
        const char* _s = (src_);                                                   \
        _Pragma("unroll")                                                          \
        for (int r2 = 0; r2 < 2; ++r2) {                                           \
            int chunk = r2 * 192 + t;                                              \
            if (r2 < 1 || t < 120)                                                 \
                __builtin_amdgcn_global_load_lds(                                  \
                    (const __attribute__((address_space(1))) unsigned int*)(_s + (size_t)chunk * 16), \
                    (__attribute__((address_space(3))) unsigned int*)(lds + (bufsel_) * QSLAB_B + chunk * 16), \
                    16, 0, 0);                                                     \
        }                                                                          \
    } while (0)

    // prologue: stage first two windows into b0, b1
    int w0 = __ffs(mask) - 1;
    unsigned m1 = mask & (mask - 1);
    STAGE(0, SLAB_PTR(w0));
    if (m1) { int w1 = __ffs(m1) - 1; STAGE(1, SLAB_PTR(w1)); }

    int cb = 0;
    int prev_row = -1;
    bf16x8 afr[3][5];   // A-frags for current ku row (kv = 0..2), static indices
    unsigned mrem = mask;

    while (mrem) {
        const int i = __ffs(mrem) - 1; mrem &= mrem - 1;
        const unsigned mn2 = mrem ? (mrem & (mrem - 1)) : 0;
        const int n2 = mn2 ? (__ffs(mn2) - 1) : -1;

        // stage(i) retired when the only newer vmem (stage(i+1), 2 ops) remains
        if (mrem) asm volatile("s_waitcnt vmcnt(2)" ::: "memory");
        else      asm volatile("s_waitcnt vmcnt(0)" ::: "memory");
        __builtin_amdgcn_s_barrier();

        const int ku = i / 6, vj = i % 6;
        if (ku != prev_row) {             // block-uniform row transition: reload A
            prev_row = ku;
            #pragma unroll
            for (int kv = 0; kv < 3; ++kv) {
                const char* ap = ws + (size_t)(ku * 3 + kv) * 5120 + (size_t)lane * 16;
                #pragma unroll
                for (int s = 0; s < 5; ++s) afr[kv][s] = *(const bf16x8*)(ap + s * 1024);
            }
        }

        const char* bp = lds + cb * QSLAB_B + wvid * 256;
        #pragma unroll
        for (int tr = 0; tr < 2; ++tr) {
            #pragma unroll
            for (int s = 0; s < 5; ++s) {
                bf16x8 bfr = *(const bf16x8*)(bp + tr * 1664 + loff[tr][s]);
                #pragma unroll
                for (int kv = 0; kv < 3; ++kv) {
                    const int a = vj - kv;            // output slab index
                    if (a >= 0 && a <= 3)
                        acc[a][tr] = __builtin_amdgcn_mfma_f32_16x16x32_bf16(afr[kv][s], bfr, acc[a][tr], 0, 0, 0);
                }
            }
        }
        __builtin_amdgcn_s_barrier();     // all waves done reading b_cb (no vmem drain)
        if (n2 >= 0) STAGE(cb, SLAB_PTR(n2));   // refill just-freed buffer, 2 iters ahead
        cb ^= 1;
    }

    // epilogue: C col = lane&15 -> (dh,dw); row = g*4+r -> c_out ; four v-slabs
    float bv[4];
    #pragma unroll
    for (int r = 0; r < 4; ++r) bv[r] = bias[g * 4 + r];
    #pragma unroll
    for (int a = 0; a < 4; ++a) {
        float* outp = out + (size_t)nb * 16 * CISTRIDE + (size_t)(u * S + v0 + a) * PLANE;
        #pragma unroll
        for (int tr = 0; tr < 2; ++tr) {
            int row = qq * 4 + tr * 2 + dh;
            int col = wvid * 8 + dw;
            int pos = row * S + col;
            #pragma unroll
            for (int r = 0; r < 4; ++r)
                outp[(size_t)(g * 4 + r) * CISTRIDE + pos] = acc[a][tr][r] + bv[r];
        }
    }
}

extern "C" void kernel_launch(void* const* d_in, const int* in_sizes, int n_in,
                              void* d_out, int out_size, void* d_ws, size_t ws_size,
                              hipStream_t stream) {
    const float* in   = (const float*)d_in[0];
    const float* wgt  = (const float*)d_in[1];
    const float* bias = (const float*)d_in[2];
    float* out        = (float*)d_out;
    char* ws          = (char*)d_ws;

    pack_in<<<dim3(1152), dim3(256), 0, stream>>>(in, wgt, ws);
    conv4d_main<<<dim3(1728), dim3(192), 0, stream>>>(ws, bias, out);
}

// Round 18
// 68.825 us; speedup vs baseline: 1.5580x; 1.5253x over previous
//
#include <hip/hip_runtime.h>

#define S 24
#define PLANE 576
#define CISTRIDE 331776          // floats per (n,ci)
#define SLAB_B 21632             // full padded slab: 676 positions * 32 B
#define QBUF_B 6144              // staged band buffer: 384 chunks * 16 B (>= 6 rows usable)
#define QOFF 3328                // 4 rows * 832 B
#define A_BYTES 46080            // 9 taps * 5 steps * 64 lanes * 16 B
#define WS_SLABS A_BYTES

typedef __attribute__((ext_vector_type(8))) short bf16x8;
typedef __attribute__((ext_vector_type(4))) float f32x4;

__device__ __forceinline__ ushort f2bf(float f) {   // round-to-nearest-even
    unsigned int u = __builtin_bit_cast(unsigned int, f);
    unsigned int r = u + 0x7fffu + ((u >> 16) & 1u);
    return (ushort)(r >> 16);
}

// ---------------- prepass: DMA-staged transpose to bf16 slabs (+ weights from block 0) ----
// slab layout: 16B chunk c for (row,col,half): byte = (c*16) ^ ((row&3)<<4), c=(row*26+col)*2+half
__global__ void __launch_bounds__(256)
pack_in(const float* __restrict__ in, const float* __restrict__ wgt, char* __restrict__ ws) {
    __shared__ __align__(16) float lds_f[16 * 576];   // 36864 B raw f32 planes

    const int b = blockIdx.x;             // 1152 slabs
    const int nb = b / PLANE, uv = b % PLANE;
    const float* src = in + (size_t)nb * 16 * CISTRIDE + (size_t)uv * PLANE;
    char* dst = ws + WS_SLABS + (size_t)b * SLAB_B;
    const int t = threadIdx.x;

    // phase 1: global->LDS DMA, 2304 16B chunks, no VGPR round-trip
    #pragma unroll
    for (int r = 0; r < 9; ++r) {
        int chunk = r * 256 + t;          // exact 9*256
        int ci = chunk / 144, q4 = chunk % 144;
        __builtin_amdgcn_global_load_lds(
            (const __attribute__((address_space(1))) unsigned int*)(src + (size_t)ci * CISTRIDE + 4 * q4),
            (__attribute__((address_space(3))) unsigned int*)(&lds_f[chunk * 4]),
            16, 0, 0);
    }
    __syncthreads();

    // phase 2: convert on read, pack 16 ci per position, swizzled coalesced stores
    #pragma unroll
    for (int i = 0; i < 6; ++i) {
        int c = i * 256 + t;              // chunk index 0..1351
        if (c < 1352) {
            int pos = c >> 1, h = c & 1;
            int row = pos / 26, col = pos % 26;
            uint4 o = make_uint4(0, 0, 0, 0);
            if (row >= 1 && row <= 24 && col >= 1 && col <= 24) {
                int q = (row - 1) * 24 + (col - 1);
                #pragma unroll
                for (int kk = 0; kk < 4; ++kk) {
                    float fa = lds_f[(8 * h + 2 * kk) * 576 + q];
                    float fb = lds_f[(8 * h + 2 * kk + 1) * 576 + q];
                    ((unsigned*)&o)[kk] = (unsigned)f2bf(fa) | ((unsigned)f2bf(fb) << 16);
                }
            }
            *(uint4*)(dst + (((size_t)c * 16) ^ (size_t)((row & 3) << 4))) = o;
        }
    }

    if (b == 0) {                        // weight A-fragments, 9 taps
        for (int i = t; i < 2880; i += 256) {
            int step = i >> 6;           // 0..44
            int tap = step / 5, s = step % 5;
            int lane = i & 63;
            int co = lane & 15, gA = lane >> 4;
            int o = 2 * s + (gA >> 1);
            int cib = (gA & 1) * 8;
            ushort vals[8];
            #pragma unroll
            for (int j = 0; j < 8; ++j)
                vals[j] = (o <= 8) ? f2bf(wgt[co * 1296 + (cib + j) * 81 + tap * 9 + o]) : (ushort)0;
            uint4 pk;
            pk.x = vals[0] | ((unsigned)vals[1] << 16);
            pk.y = vals[2] | ((unsigned)vals[3] << 16);
            pk.z = vals[4] | ((unsigned)vals[5] << 16);
            pk.w = vals[6] | ((unsigned)vals[7] << 16);
            *(uint4*)(ws + (size_t)i * 16) = pk;
        }
    }
}

// ---- main: G=4 v-adjacent outputs, 6 h-bands, STATIC T4 counted-vmcnt schedule ----
__global__ void __launch_bounds__(192, 4)
conv4d_main(const char* __restrict__ ws, const float* __restrict__ bias,
            float* __restrict__ out) {
    __shared__ __align__(16) char lds[2 * QBUF_B];   // 12288 B double buffer

    const int t = threadIdx.x, lane = t & 63, wvid = t >> 6;   // wave = 8-col band
    // XCD-chunked bijective swizzle: 1728 ids, 8 XCDs x 216 contiguous
    const int braw = blockIdx.x;
    const int b = (braw & 7) * 216 + (braw >> 3);
    const int nb = b / 864, rem = b % 864;
    const int u = rem / 36, rem2 = rem % 36;
    const int v0 = (rem2 / 6) * 4, qq = rem2 % 6;     // 4 v-slabs, 4-row band

    const int n16 = lane & 15, g = lane >> 4;
    const int dh = n16 >> 3, dw = n16 & 7;            // 2x8 position tile
    const int half = g & 1, osel = g >> 1;

    // per-(tr,s) B offsets; band base row = 4*qq ≡ 0 mod 4 -> phase = (2*tr + r_off)&3
    int loff[2][5];
    #pragma unroll
    for (int tr = 0; tr < 2; ++tr)
        #pragma unroll
        for (int s = 0; s < 5; ++s) {
            int o = 2 * s + osel; if (o > 8) o = 8;   // K-tail clamp (A is zero there)
            int kh = o / 3, kw = o % 3;
            int r_off = dh + kh, c_off = dw + kw;
            int lin = (r_off * 26 + c_off) * 32 + half * 16;
            loff[tr][s] = lin ^ (((tr * 2 + r_off) & 3) << 4);
        }

    f32x4 acc[4][2];
    #pragma unroll
    for (int a = 0; a < 4; ++a)
        #pragma unroll
        for (int tr = 0; tr < 2; ++tr) acc[a][tr] = (f32x4){0, 0, 0, 0};

    // window mask: w = ku*6 + vj ; uu = u+ku-1, vv = v0+vj-1 (block-uniform)
    unsigned mask = 0;
    #pragma unroll
    for (int i = 0; i < 18; ++i) {
        int uu = u + i / 6 - 1, vv = v0 + i % 6 - 1;
        if (uu >= 0 && uu < S && vv >= 0 && vv < S) mask |= 1u << i;
    }

    const char* slabs = ws + WS_SLABS;
    const size_t qoff = (size_t)qq * QOFF;
    // clamped pointer: always valid memory; invalid windows stage unused-but-safe data
    #define SPTR(w_) (slabs + ((size_t)nb * PLANE                                        \
        + (size_t)min(max(u + (w_) / 6 - 1, 0), 23) * S                                  \
        + (size_t)min(max(v0 + (w_) % 6 - 1, 0), 23)) * SLAB_B + qoff)

    // STAGE = exactly 2 unmasked global_load_lds per wave (uniform vmcnt accounting)
    #define STAGE(bufsel_, src_) do {                                                    \
        const char* _s = (src_);                                                         \
        _Pragma("unroll")                                                                \
        for (int r2 = 0; r2 < 2; ++r2) {                                                 \
            int chunk = r2 * 192 + t;                                                    \
            __builtin_amdgcn_global_load_lds(                                            \
                (const __attribute__((address_space(1))) unsigned int*)(_s + (size_t)chunk * 16), \
                (__attribute__((address_space(3))) unsigned int*)(lds + (bufsel_) * QBUF_B + chunk * 16), \
                16, 0, 0);                                                               \
        }                                                                                \
    } while (0)

    STAGE(0, SPTR(0));
    STAGE(1, SPTR(1));

    bf16x8 afr[3][5];   // A-frags for current ku row, static indices

    #pragma unroll
    for (int w = 0; w < 18; ++w) {
        // stage(w) retired when only stage(w+1) (2 ops/wave) remains in flight
        if (w <= 16) asm volatile("s_waitcnt vmcnt(2)" ::: "memory");
        else         asm volatile("s_waitcnt vmcnt(0)" ::: "memory");
        __builtin_amdgcn_s_barrier();

        if ((w % 6) == 0) {               // compile-time row transition: reload A row
            const int ku = w / 6;
            #pragma unroll
            for (int kv = 0; kv < 3; ++kv) {
                const char* ap = ws + (size_t)(ku * 3 + kv) * 5120 + (size_t)lane * 16;
                #pragma unroll
                for (int s = 0; s < 5; ++s) afr[kv][s] = *(const bf16x8*)(ap + s * 1024);
            }
        }

        if (mask & (1u << w)) {           // block-uniform branch
            const int vj = w % 6;         // compile-time
            const char* bp = lds + (w & 1) * QBUF_B + wvid * 256;
            #pragma unroll
            for (int tr = 0; tr < 2; ++tr) {
                #pragma unroll
                for (int s = 0; s < 5; ++s) {
                    bf16x8 bfr = *(const bf16x8*)(bp + tr * 1664 + loff[tr][s]);
                    #pragma unroll
                    for (int kv = 0; kv < 3; ++kv) {
                        const int a = vj - kv;        // compile-time output slab index
                        if (a >= 0 && a <= 3)
                            acc[a][tr] = __builtin_amdgcn_mfma_f32_16x16x32_bf16(afr[kv][s], bfr, acc[a][tr], 0, 0, 0);
                    }
                }
            }
        }
        __builtin_amdgcn_s_barrier();     // all waves done reading buf(w&1); no vmem drain
        if (w + 2 < 18) STAGE(w & 1, SPTR(w + 2));   // refill freed buffer, lands by wait(w+2)
    }

    // epilogue: C col = lane&15 -> (dh,dw); row = g*4+r -> c_out ; four v-slabs
    float bv[4];
    #pragma unroll
    for (int r = 0; r < 4; ++r) bv[r] = bias[g * 4 + r];
    #pragma unroll
    for (int a = 0; a < 4; ++a) {
        float* outp = out + (size_t)nb * 16 * CISTRIDE + (size_t)(u * S + v0 + a) * PLANE;
        #pragma unroll
        for (int tr = 0; tr < 2; ++tr) {
            int row = qq * 4 + tr * 2 + dh;
            int col = wvid * 8 + dw;
            int pos = row * S + col;
            #pragma unroll
            for (int r = 0; r < 4; ++r)
                outp[(size_t)(g * 4 + r) * CISTRIDE + pos] = acc[a][tr][r] + bv[r];
        }
    }
}

extern "C" void kernel_launch(void* const* d_in, const int* in_sizes, int n_in,
                              void* d_out, int out_size, void* d_ws, size_t ws_size,
                              hipStream_t stream) {
    const float* in   = (const float*)d_in[0];
    const float* wgt  = (const float*)d_in[1];
    const float* bias = (const float*)d_in[2];
    float* out        = (float*)d_out;
    char* ws          = (char*)d_ws;

    pack_in<<<dim3(1152), dim3(256), 0, stream>>>(in, wgt, ws);
    conv4d_main<<<dim3(1728), dim3(192), 0, stream>>>(ws, bias, out);
}